// Round 5
// baseline (993.779 us; speedup 1.0000x reference)
//
#include <hip/hip_runtime.h>
#include <math.h>

#define NC    512
#define NG    4
#define NCG   128          // C / G
#define NR    16           // reduced dim
#define NTOPK 384
#define NB    16
#define HW    (112 * 112)  // 12544
#define NBLK  512          // one block per channel
#define ALPHA 0.1f
#define EPSC  1e-8f

typedef float f32x4 __attribute__((ext_vector_type(4)));

// 3136 float4 per channel = 12*256 + 64 tail. Thread t owns j*256+t (+ tail).
__device__ __forceinline__ void load_ch(f32x4* __restrict__ buf,
                                        const float* __restrict__ base, int t) {
  const f32x4* p = reinterpret_cast<const f32x4*>(base);
  #pragma unroll
  for (int j = 0; j < 12; ++j)
    buf[j] = __builtin_nontemporal_load(&p[t + 256 * j]);
  if (t < 64) buf[12] = __builtin_nontemporal_load(&p[3072 + t]);
}

__device__ __forceinline__ void reduce_ch(const f32x4* __restrict__ buf, int t,
                                          float& s_out, float& m_out,
                                          float* red_s, float* red_m) {
  float s = 0.f, m = -INFINITY;
  #pragma unroll
  for (int j = 0; j < 12; ++j) {
    f32x4 v = buf[j];
    s += (v.x + v.y) + (v.z + v.w);
    m = fmaxf(m, fmaxf(fmaxf(v.x, v.y), fmaxf(v.z, v.w)));
  }
  if (t < 64) {
    f32x4 v = buf[12];
    s += (v.x + v.y) + (v.z + v.w);
    m = fmaxf(m, fmaxf(fmaxf(v.x, v.y), fmaxf(v.z, v.w)));
  }
  #pragma unroll
  for (int off = 32; off; off >>= 1) {
    s += __shfl_down(s, off, 64);
    m = fmaxf(m, __shfl_down(m, off, 64));
  }
  if ((t & 63) == 0) { red_s[t >> 6] = s; red_m[t >> 6] = m; }
  __syncthreads();
  s_out = (red_s[0] + red_s[1]) + (red_s[2] + red_s[3]);
  m_out = fmaxf(fmaxf(red_m[0], red_m[1]), fmaxf(red_m[2], red_m[3]));
  __syncthreads();  // red_* reusable afterwards
}

template <bool HAS_NEXT>
__device__ __forceinline__ void do_phase(
    int k, int c, int t, f32x4* __restrict__ cur, f32x4* __restrict__ nxt,
    const float* __restrict__ x, const float* __restrict__ W1,
    const float* __restrict__ b1, const float* __restrict__ W2,
    const float* __restrict__ b2, const float* __restrict__ noise_u,
    float* __restrict__ out, float* __restrict__ ws_s,
    float* __restrict__ ws_m, unsigned int* __restrict__ ctr,
    float* comb, float* sc, float* h, float* red_s, float* red_m,
    int* red_i, float* blend_sh) {
  // 1) issue next-batch loads FIRST — they stream while we wait at the barrier
  if (HAS_NEXT) load_ch(nxt, x + ((size_t)(k + 1) * NC + c) * HW, t);

  // 2) wait for epoch k: all 512 blocks posted (sum,max) of batch k
  if (t == 0) {
    const unsigned target = (unsigned)NBLK * (unsigned)(k + 1);
    while (__hip_atomic_load(ctr, __ATOMIC_ACQUIRE,
                             __HIP_MEMORY_SCOPE_AGENT) < target)
      __builtin_amdgcn_s_sleep(2);
  }
  __syncthreads();

  // 3) stage pooled features (agent-scope atomic loads — XCD-coherent)
  const int p = k & 1;
  #pragma unroll
  for (int q = 0; q < 2; ++q) {
    const int cc2 = t + q * 256;
    float sv = __hip_atomic_load(&ws_s[p * NC + cc2], __ATOMIC_RELAXED,
                                 __HIP_MEMORY_SCOPE_AGENT);
    float mv = __hip_atomic_load(&ws_m[p * NC + cc2], __ATOMIC_RELAXED,
                                 __HIP_MEMORY_SCOPE_AGENT);
    comb[cc2]      = sv * (1.0f / (float)HW);
    comb[NC + cc2] = mv;
  }
  __syncthreads();

  // 4) MLP1: 64 outputs, 4 threads each
  {
    const int pair = t >> 2, sub = t & 3;
    const int g = pair >> 4, r = pair & 15;
    const float* cf = comb + g * (2 * NCG);
    const float* w  = W1 + (size_t)g * (2 * NCG) * NR + r;
    const int i0 = sub * 64;
    float acc = 0.f;
    #pragma unroll 8
    for (int i = 0; i < 64; ++i) acc += cf[i0 + i] * w[(i0 + i) * NR];
    acc += __shfl_down(acc, 2, 4);
    acc += __shfl_down(acc, 1, 4);
    if (sub == 0) h[pair] = fmaxf(acc + b1[g * NR + r], 0.f);
  }
  __syncthreads();

  // 5) MLP2: all 512 scores (rank needs them all)
  #pragma unroll
  for (int cc = 0; cc < 2; ++cc) {
    const int ch = t + cc * 256;
    const int g = ch >> 7, o = ch & 127;
    float acc = b2[g * NCG + o];
    const float* w  = W2 + (size_t)g * NR * NCG + o;
    const float* hh = h + g * NR;
    #pragma unroll
    for (int r = 0; r < NR; ++r) acc += hh[r] * w[r * NCG];
    sc[ch] = acc;
  }
  __syncthreads();

  // 6) exact rank of OUR channel c (stable lowest-index tie-break)
  const float my = sc[c];
  int cnt = 0;
  { float v = sc[t];       cnt += (v > my) || (v == my && t < c); }
  { float v = sc[t + 256]; cnt += (v > my) || (v == my && (t + 256) < c); }
  #pragma unroll
  for (int off = 32; off; off >>= 1) cnt += __shfl_down(cnt, off, 64);
  if ((t & 63) == 0) red_i[t >> 6] = cnt;
  __syncthreads();
  if (t == 0) {
    const int ct = red_i[0] + red_i[1] + red_i[2] + red_i[3];
    const float hard = (ct < NTOPK) ? 1.f : 0.f;
    const float u = noise_u[(size_t)k * NC + c];
    const float gum = -logf(-logf(u + EPSC) + EPSC);
    const float soft = 1.f / (1.f + expf(-(my + gum) * 2.0f));  // TAU=0.5
    const float mask = hard * soft;
    *blend_sh = mask + (1.f - mask) * ALPHA;
  }
  __syncthreads();
  const float bl = *blend_sh;

  // 7) scale the register-resident batch k and stream out (NT)
  {
    f32x4* q = reinterpret_cast<f32x4*>(out + ((size_t)k * NC + c) * HW);
    #pragma unroll
    for (int j = 0; j < 12; ++j)
      __builtin_nontemporal_store(cur[j] * bl, &q[t + 256 * j]);
    if (t < 64) __builtin_nontemporal_store(cur[12] * bl, &q[3072 + t]);
  }

  // 8) reduce prefetched batch k+1, post sums, signal epoch k+1
  if (HAS_NEXT) {
    float s2, m2;
    reduce_ch(nxt, t, s2, m2, red_s, red_m);
    if (t == 0) {
      const int p2 = (k + 1) & 1;
      __hip_atomic_store(&ws_s[p2 * NC + c], s2, __ATOMIC_RELAXED,
                         __HIP_MEMORY_SCOPE_AGENT);
      __hip_atomic_store(&ws_m[p2 * NC + c], m2, __ATOMIC_RELAXED,
                         __HIP_MEMORY_SCOPE_AGENT);
      __hip_atomic_fetch_add(ctr, 1u, __ATOMIC_RELEASE,
                             __HIP_MEMORY_SCOPE_AGENT);
    }
  }
}

__global__ void init_ctr_kernel(unsigned int* ctr) { *ctr = 0u; }

// Persistent kernel: block = channel, phase = batch. x read ONCE from HBM.
__global__ __launch_bounds__(256, 3) void mega_kernel(
    const float* __restrict__ x, const float* __restrict__ W1,
    const float* __restrict__ b1, const float* __restrict__ W2,
    const float* __restrict__ b2, const float* __restrict__ noise_u,
    float* __restrict__ out, float* __restrict__ ws_s,
    float* __restrict__ ws_m, unsigned int* __restrict__ ctr) {
  const int c = blockIdx.x;
  const int t = threadIdx.x;

  __shared__ float comb[2 * NC];
  __shared__ float sc[NC];
  __shared__ float h[NG * NR];
  __shared__ float red_s[4], red_m[4];
  __shared__ int   red_i[4];
  __shared__ float blend_sh;

  f32x4 A[13], B[13];

  // prologue: pool batch 0 into registers, post sums, signal epoch 0
  load_ch(A, x + (size_t)c * HW, t);
  {
    float s0, m0;
    reduce_ch(A, t, s0, m0, red_s, red_m);
    if (t == 0) {
      __hip_atomic_store(&ws_s[c], s0, __ATOMIC_RELAXED,
                         __HIP_MEMORY_SCOPE_AGENT);
      __hip_atomic_store(&ws_m[c], m0, __ATOMIC_RELAXED,
                         __HIP_MEMORY_SCOPE_AGENT);
      __hip_atomic_fetch_add(ctr, 1u, __ATOMIC_RELEASE,
                             __HIP_MEMORY_SCOPE_AGENT);
    }
  }

  // 16 phases; A/B alternate via static call pattern (no runtime indexing)
  #define PH(K, HASN, CUR, NXT)                                             \
    do_phase<HASN>(K, c, t, CUR, NXT, x, W1, b1, W2, b2, noise_u, out,      \
                   ws_s, ws_m, ctr, comb, sc, h, red_s, red_m, red_i,       \
                   &blend_sh)
  for (int kp = 0; kp < 7; ++kp) {
    PH(2 * kp,     true, A, B);
    PH(2 * kp + 1, true, B, A);
  }
  PH(14, true,  A, B);
  PH(15, false, B, A);
  #undef PH
}

extern "C" void kernel_launch(void* const* d_in, const int* in_sizes, int n_in,
                              void* d_out, int out_size, void* d_ws, size_t ws_size,
                              hipStream_t stream) {
  const float* x       = (const float*)d_in[0];
  const float* W1      = (const float*)d_in[1];
  const float* b1      = (const float*)d_in[2];
  const float* W2      = (const float*)d_in[3];
  const float* b2      = (const float*)d_in[4];
  const float* noise_u = (const float*)d_in[5];
  float* out = (float*)d_out;

  unsigned int* ctr = (unsigned int*)d_ws;                  // 1 counter
  float* ws_s = (float*)((char*)d_ws + 256);                // [2][512]
  float* ws_m = ws_s + 2 * NC;                              // [2][512]

  init_ctr_kernel<<<1, 1, 0, stream>>>(ctr);
  mega_kernel<<<NBLK, 256, 0, stream>>>(x, W1, b1, W2, b2, noise_u, out,
                                        ws_s, ws_m, ctr);
}

// Round 6
// 231.293 us; speedup vs baseline: 4.2966x; 4.2966x over previous
//
#include <hip/hip_runtime.h>
#include <math.h>

#define NC    512
#define NG    4
#define NCG   128          // C / G
#define NR    16           // reduced dim
#define NTOPK 384
#define NB    16
#define HW    (112 * 112)  // 12544
#define ALPHA 0.1f
#define EPSC  1e-8f

#define CHUNK      4                 // batches per chunk (103 MB)
#define NCHUNK     (NB / CHUNK)      // 4
#define BC_PER_CH  (CHUNK * NC)      // 2048 pool blocks per chunk
#define SCALE_BLKS (CHUNK * 64)      // 256 scale blocks per chunk (8 ch each)

typedef float f32x4 __attribute__((ext_vector_type(4)));

// ---- pool one (b,c) tile: cached loads (allocate in L3 for the re-read) ----
__device__ __forceinline__ void pool_one(const float* __restrict__ x, int bc,
                                         float* __restrict__ avg_out,
                                         float* __restrict__ max_out,
                                         float* ss, float* sm) {
  const int t = threadIdx.x;
  const f32x4* p = reinterpret_cast<const f32x4*>(x + (size_t)bc * HW);
  float s = 0.f;
  float m = -INFINITY;
  for (int i = t; i < 3072; i += 1024) {
    f32x4 v0 = p[i];
    f32x4 v1 = p[i + 256];
    f32x4 v2 = p[i + 512];
    f32x4 v3 = p[i + 768];
    s += (v0.x + v0.y) + (v0.z + v0.w);
    s += (v1.x + v1.y) + (v1.z + v1.w);
    s += (v2.x + v2.y) + (v2.z + v2.w);
    s += (v3.x + v3.y) + (v3.z + v3.w);
    m = fmaxf(m, fmaxf(fmaxf(v0.x, v0.y), fmaxf(v0.z, v0.w)));
    m = fmaxf(m, fmaxf(fmaxf(v1.x, v1.y), fmaxf(v1.z, v1.w)));
    m = fmaxf(m, fmaxf(fmaxf(v2.x, v2.y), fmaxf(v2.z, v2.w)));
    m = fmaxf(m, fmaxf(fmaxf(v3.x, v3.y), fmaxf(v3.z, v3.w)));
  }
  if (t < 64) {
    f32x4 v = p[3072 + t];
    s += (v.x + v.y) + (v.z + v.w);
    m = fmaxf(m, fmaxf(fmaxf(v.x, v.y), fmaxf(v.z, v.w)));
  }
  #pragma unroll
  for (int off = 32; off > 0; off >>= 1) {
    s += __shfl_down(s, off, 64);
    m = fmaxf(m, __shfl_down(m, off, 64));
  }
  const int wave = t >> 6, lane = t & 63;
  if (lane == 0) { ss[wave] = s; sm[wave] = m; }
  __syncthreads();
  if (t == 0) {
    float st = (ss[0] + ss[1]) + (ss[2] + ss[3]);
    float mt = fmaxf(fmaxf(sm[0], sm[1]), fmaxf(sm[2], sm[3]));
    avg_out[bc] = st / (float)HW;
    max_out[bc] = mt;
  }
}

// ---- scale part: block rb in [0,SCALE_BLKS) of chunk ch; owns 8 channels ----
__device__ __forceinline__ void scale_part(
    int ch, int rb, const float* __restrict__ x, const float* __restrict__ avg,
    const float* __restrict__ mx, const float* __restrict__ W1,
    const float* __restrict__ b1, const float* __restrict__ W2,
    const float* __restrict__ b2, const float* __restrict__ noise_u,
    float* __restrict__ out, float* comb, float* sc, float* h,
    float* blend_loc) {
  const int b  = ch * CHUNK + (rb >> 6);  // global batch
  const int c0 = (rb & 63) * 8;
  const int t  = threadIdx.x;

  {  // pooled features of batch b (written by previous kernel's pool part)
    const float* pa = avg + b * NC;
    const float* pm = mx  + b * NC;
    comb[t]             = pa[t];
    comb[t + 256]       = pa[t + 256];
    comb[512 + t]       = pm[t];
    comb[512 + t + 256] = pm[t + 256];
  }
  __syncthreads();

  {  // MLP1: 64 outputs, 4 threads each
    const int pair = t >> 2, sub = t & 3;
    const int g = pair >> 4, r = pair & 15;
    const float* cf = comb + g * (2 * NCG);
    const float* w  = W1 + (size_t)g * (2 * NCG) * NR + r;
    const int i0 = sub * 64;
    float acc = 0.f;
    #pragma unroll 8
    for (int i = 0; i < 64; ++i) acc += cf[i0 + i] * w[(i0 + i) * NR];
    acc += __shfl_down(acc, 2, 4);
    acc += __shfl_down(acc, 1, 4);
    if (sub == 0) h[pair] = fmaxf(acc + b1[g * NR + r], 0.f);
  }
  __syncthreads();

  #pragma unroll
  for (int cc = 0; cc < 2; ++cc) {  // MLP2: 512 scores
    const int c = t + cc * 256;
    const int g = c >> 7, o = c & 127;
    float acc = b2[g * NCG + o];
    const float* w  = W2 + (size_t)g * NR * NCG + o;
    const float* hh = h + g * NR;
    #pragma unroll
    for (int r = 0; r < NR; ++r) acc += hh[r] * w[r * NCG];
    sc[c] = acc;
  }
  __syncthreads();

  {  // exact rank for our 8 channels (32 threads per channel)
    const int ci = t >> 5, sub = t & 31;
    const int c = c0 + ci;
    const float my = sc[c];
    int cnt = 0;
    const int j0 = sub * 16;
    #pragma unroll
    for (int jj = 0; jj < 16; ++jj) {
      const int j = j0 + jj;
      const float v = sc[j];
      cnt += (v > my) || (v == my && j < c);
    }
    cnt += __shfl_down(cnt, 16, 32);
    cnt += __shfl_down(cnt,  8, 32);
    cnt += __shfl_down(cnt,  4, 32);
    cnt += __shfl_down(cnt,  2, 32);
    cnt += __shfl_down(cnt,  1, 32);
    if (sub == 0) {
      const float hard = (cnt < NTOPK) ? 1.f : 0.f;
      const float u = noise_u[b * NC + c];
      const float gum = -logf(-logf(u + EPSC) + EPSC);
      const float soft = 1.f / (1.f + expf(-(my + gum) * 2.0f));  // TAU=0.5
      const float mask = hard * soft;
      blend_loc[ci] = mask + (1.f - mask) * ALPHA;
    }
  }
  __syncthreads();

  // scale 8 tiles: reads should hit L3 (chunk pooled by previous kernel)
  for (int k = 0; k < 8; ++k) {
    const int bc = (b * NC) + c0 + k;
    const float s = blend_loc[k];
    const f32x4* p = reinterpret_cast<const f32x4*>(x + (size_t)bc * HW);
    f32x4* q = reinterpret_cast<f32x4*>(out + (size_t)bc * HW);
    for (int i = t; i < 3072; i += 1024) {
      f32x4 v0 = p[i];
      f32x4 v1 = p[i + 256];
      f32x4 v2 = p[i + 512];
      f32x4 v3 = p[i + 768];
      v0 *= s; v1 *= s; v2 *= s; v3 *= s;
      __builtin_nontemporal_store(v0, &q[i]);
      __builtin_nontemporal_store(v1, &q[i + 256]);
      __builtin_nontemporal_store(v2, &q[i + 512]);
      __builtin_nontemporal_store(v3, &q[i + 768]);
    }
    if (t < 64) {
      const int i = 3072 + t;
      f32x4 v = p[i];
      v *= s;
      __builtin_nontemporal_store(v, &q[i]);
    }
  }
}

// ---- P0: pool chunk 0 only ----
__global__ __launch_bounds__(256) void pool_kernel(
    const float* __restrict__ x, float* __restrict__ avg_out,
    float* __restrict__ max_out) {
  __shared__ float ss[4], sm[4];
  pool_one(x, blockIdx.x, avg_out, max_out, ss, sm);
}

// ---- Fi: scale chunk ch (blocks 0..255) + pool chunk ch+1 (blocks 256..2303)
// F3 is launched with only 256 blocks => scale-only.
__global__ __launch_bounds__(256) void combo_kernel(
    const float* __restrict__ x, float* __restrict__ avg,
    float* __restrict__ mx, const float* __restrict__ W1,
    const float* __restrict__ b1, const float* __restrict__ W2,
    const float* __restrict__ b2, const float* __restrict__ noise_u,
    float* __restrict__ out, int ch) {
  __shared__ float comb[2 * NC];   // scale path
  __shared__ float sc[NC];
  __shared__ float h[NG * NR];
  __shared__ float blend_loc[8];
  __shared__ float ss[4], sm[4];   // pool path

  if (blockIdx.x < SCALE_BLKS) {
    scale_part(ch, blockIdx.x, x, avg, mx, W1, b1, W2, b2, noise_u, out,
               comb, sc, h, blend_loc);
  } else {
    const int bc = (ch + 1) * BC_PER_CH + ((int)blockIdx.x - SCALE_BLKS);
    pool_one(x, bc, avg, mx, ss, sm);
  }
}

extern "C" void kernel_launch(void* const* d_in, const int* in_sizes, int n_in,
                              void* d_out, int out_size, void* d_ws, size_t ws_size,
                              hipStream_t stream) {
  const float* x       = (const float*)d_in[0];
  const float* W1      = (const float*)d_in[1];
  const float* b1      = (const float*)d_in[2];
  const float* W2      = (const float*)d_in[3];
  const float* b2      = (const float*)d_in[4];
  const float* noise_u = (const float*)d_in[5];
  float* out = (float*)d_out;

  float* ws_avg = (float*)d_ws;        // B*C floats
  float* ws_max = ws_avg + NB * NC;    // B*C floats

  pool_kernel<<<BC_PER_CH, 256, 0, stream>>>(x, ws_avg, ws_max);
  for (int ch = 0; ch < NCHUNK; ++ch) {
    const int nblk = (ch + 1 < NCHUNK) ? (SCALE_BLKS + BC_PER_CH) : SCALE_BLKS;
    combo_kernel<<<nblk, 256, 0, stream>>>(x, ws_avg, ws_max, W1, b1, W2, b2,
                                           noise_u, out, ch);
  }
}